// Round 5
// baseline (96.048 us; speedup 1.0000x reference)
//
#include <hip/hip_runtime.h>
#include <hip/hip_bf16.h>

// DEC ClusteringLayer: q[i][j] = (1/(1+||x_i-c_j||^2)) / rowsum, ALPHA=1.
// Barrier-free, LDS-free K-loop: A fragments loaded per-lane straight from
// global x (fp32) and converted in-register; B (clusters, bf16, L2-resident)
// pre-packed in fragment order, loaded straight into MFMA operands.
// Round 5: B prefetched ONE BODY ahead (named Bc/Bn, literal indices only —
// rule #20), X two bodies ahead; loads issued before the compute that hides them.

typedef __attribute__((ext_vector_type(8))) short short8v;
typedef __attribute__((ext_vector_type(4))) float f32x4;

#define DDIM 512
#define KCL  256
#define BM   64
#define NT   512
#define NTILES 16        // DDIM / 32
#define BTILE  8192      // shorts per fragment-order B image (256x32)

__device__ __forceinline__ short f2bf(float f) {
    __hip_bfloat16 h = __float2bfloat16(f);
    return __builtin_bit_cast(short, h);
}

// ---- pre-kernel: blocks 0..63 pack clusters -> bf16 fragment-order images;
//      blocks 64..79 compute ||c||^2 ----
__global__ void prep(const float* __restrict__ cl, short* __restrict__ wsB,
                     float* __restrict__ wsC2) {
    const int t = threadIdx.x;
    if (blockIdx.x < 64) {
        const int u = blockIdx.x * 256 + t;            // granule id
        const int img = u >> 10, gi = u & 1023;
        const int g = gi >> 6, lq = (gi >> 4) & 3, l15 = gi & 15;
        const float* src = cl + (size_t)(g * 16 + l15) * DDIM + img * 32 + lq * 8;
        float4 a = *(const float4*)src;
        float4 b = *(const float4*)(src + 4);
        short8v s;
        s[0]=f2bf(a.x); s[1]=f2bf(a.y); s[2]=f2bf(a.z); s[3]=f2bf(a.w);
        s[4]=f2bf(b.x); s[5]=f2bf(b.y); s[6]=f2bf(b.z); s[7]=f2bf(b.w);
        *(short8v*)&wsB[(size_t)u * 8] = s;
    } else {
        const int cidx = (blockIdx.x - 64) * 16 + (t >> 4);
        const int j = t & 15;
        const float* src = cl + (size_t)cidx * DDIM + j * 32;
        float s = 0.f;
#pragma unroll
        for (int i = 0; i < 8; ++i) {
            float4 v = ((const float4*)src)[i];
            s += v.x*v.x + v.y*v.y + v.z*v.z + v.w*v.w;
        }
        s += __shfl_xor(s, 1); s += __shfl_xor(s, 2);
        s += __shfl_xor(s, 4); s += __shfl_xor(s, 8);
        if (j == 0) wsC2[cidx] = s;
    }
}

// ---- main: 64 rows x 256 clusters per block, 8 waves (2 row-grp x 4 col-grp) ----
__global__ __launch_bounds__(NT, 4)
void dec_main(const float* __restrict__ x, const short* __restrict__ wsB,
              const float* __restrict__ wsC2, float* __restrict__ out) {
    __shared__ float s_x2[BM];
    __shared__ float s_rs[4][BM];

    const int t = threadIdx.x, lane = t & 63, w = t >> 6;
    const int rg = w >> 2, cg = w & 3;
    const int l15 = lane & 15, lq = lane >> 4;
    const int row0 = blockIdx.x * BM;

    // per-lane A sources: row rg*32 + l15 (frag a0) and +16 (frag a1), cols lq*8..+7
    const float* xr0 = x + (size_t)(row0 + rg*32 + l15) * DDIM + lq * 8;
    const float* xr1 = xr0 + (size_t)16 * DDIM;
    // B fragment base: image tt at bb + tt*BTILE, fragment n at + n*512
    const short* bb = wsB + (size_t)(cg*4) * 512 + (size_t)lane * 8;

    f32x4 acc[2][4];
#pragma unroll
    for (int m = 0; m < 2; ++m)
#pragma unroll
        for (int n = 0; n < 4; ++n) acc[m][n] = (f32x4){0.f,0.f,0.f,0.f};
    float x2a = 0.f, x2b = 0.f;

    short8v Bc[4], Bn[4];          // current / next-body B fragments (literal idx only)
    float4 Xc[4], Xn[4];           // 2-body-deep X prefetch

#define LOADX(TT, XB)                                        \
    {  XB[0] = *(const float4*)(xr0 + (TT) * 32);            \
       XB[1] = *(const float4*)(xr0 + (TT) * 32 + 4);        \
       XB[2] = *(const float4*)(xr1 + (TT) * 32);            \
       XB[3] = *(const float4*)(xr1 + (TT) * 32 + 4); }

#define LOADB(TT, BB)                                        \
    {  const short* bt = bb + (size_t)(TT) * BTILE;          \
       BB[0] = *(const short8v*)(bt);                        \
       BB[1] = *(const short8v*)(bt + 512);                  \
       BB[2] = *(const short8v*)(bt + 1024);                 \
       BB[3] = *(const short8v*)(bt + 1536); }

    // body TT: issue B(TT+1) into BNX, convert X(TT), issue X(TT+2) into XB,
    // then MFMA against BCU (loaded one body ago).
#define BODY(TT, XB, BCU, BNX)                                                   \
    {  if ((TT) + 1 < NTILES) LOADB((TT) + 1, BNX);                              \
       short8v a0, a1;                                                           \
       {  float4 p = XB[0], q = XB[1], r2 = XB[2], s2 = XB[3];                   \
          a0[0]=f2bf(p.x); a0[1]=f2bf(p.y); a0[2]=f2bf(p.z); a0[3]=f2bf(p.w);    \
          a0[4]=f2bf(q.x); a0[5]=f2bf(q.y); a0[6]=f2bf(q.z); a0[7]=f2bf(q.w);    \
          a1[0]=f2bf(r2.x); a1[1]=f2bf(r2.y); a1[2]=f2bf(r2.z); a1[3]=f2bf(r2.w);\
          a1[4]=f2bf(s2.x); a1[5]=f2bf(s2.y); a1[6]=f2bf(s2.z); a1[7]=f2bf(s2.w);\
          x2a += p.x*p.x + p.y*p.y + p.z*p.z + p.w*p.w                           \
               + q.x*q.x + q.y*q.y + q.z*q.z + q.w*q.w;                          \
          x2b += r2.x*r2.x + r2.y*r2.y + r2.z*r2.z + r2.w*r2.w                   \
               + s2.x*s2.x + s2.y*s2.y + s2.z*s2.z + s2.w*s2.w; }                \
       if ((TT) + 2 < NTILES) LOADX((TT) + 2, XB);                               \
       acc[0][0] = __builtin_amdgcn_mfma_f32_16x16x32_bf16(a0, BCU[0], acc[0][0], 0,0,0); \
       acc[0][1] = __builtin_amdgcn_mfma_f32_16x16x32_bf16(a0, BCU[1], acc[0][1], 0,0,0); \
       acc[0][2] = __builtin_amdgcn_mfma_f32_16x16x32_bf16(a0, BCU[2], acc[0][2], 0,0,0); \
       acc[0][3] = __builtin_amdgcn_mfma_f32_16x16x32_bf16(a0, BCU[3], acc[0][3], 0,0,0); \
       acc[1][0] = __builtin_amdgcn_mfma_f32_16x16x32_bf16(a1, BCU[0], acc[1][0], 0,0,0); \
       acc[1][1] = __builtin_amdgcn_mfma_f32_16x16x32_bf16(a1, BCU[1], acc[1][1], 0,0,0); \
       acc[1][2] = __builtin_amdgcn_mfma_f32_16x16x32_bf16(a1, BCU[2], acc[1][2], 0,0,0); \
       acc[1][3] = __builtin_amdgcn_mfma_f32_16x16x32_bf16(a1, BCU[3], acc[1][3], 0,0,0); }

    // prologue: X tiles 0,1 and B tile 0 in flight
    LOADX(0, Xc);
    LOADX(1, Xn);
    LOADB(0, Bc);

#pragma unroll
    for (int tt = 0; tt < NTILES; tt += 2) {
        BODY(tt,     Xc, Bc, Bn);
        BODY(tt + 1, Xn, Bn, Bc);
    }

    // ---- ||x||^2: lanes sharing l15 (lq=0..3) hold disjoint k-ranges ----
    x2a += __shfl_xor(x2a, 16); x2a += __shfl_xor(x2a, 32);
    x2b += __shfl_xor(x2b, 16); x2b += __shfl_xor(x2b, 32);
    if (cg == 0 && lq == 0) {
        s_x2[rg*32 + l15]      = x2a;
        s_x2[rg*32 + 16 + l15] = x2b;
    }
    __syncthreads();

    // ---- epilogue: d2 -> q_unnorm (C/D: col=l15, row=lq*4+r) ----
    float c2a[4];
#pragma unroll
    for (int n = 0; n < 4; ++n) c2a[n] = wsC2[cg*64 + n*16 + l15];

#pragma unroll
    for (int m = 0; m < 2; ++m)
#pragma unroll
        for (int n = 0; n < 4; ++n)
#pragma unroll
            for (int r = 0; r < 4; ++r) {
                const int rw = rg*32 + m*16 + lq*4 + r;
                float d2 = fmaxf(s_x2[rw] + c2a[n] - 2.0f * acc[m][n][r], 0.0f);
                acc[m][n][r] = 1.0f / (1.0f + d2);
            }

    // ---- row sums: 16-lane shuffle, per-cg slot (deterministic) ----
#pragma unroll
    for (int m = 0; m < 2; ++m)
#pragma unroll
        for (int r = 0; r < 4; ++r) {
            float p = acc[m][0][r] + acc[m][1][r] + acc[m][2][r] + acc[m][3][r];
            p += __shfl_xor(p, 1); p += __shfl_xor(p, 2);
            p += __shfl_xor(p, 4); p += __shfl_xor(p, 8);
            if (l15 == 0) s_rs[cg][rg*32 + m*16 + lq*4 + r] = p;
        }
    __syncthreads();

    // ---- normalize + store ----
#pragma unroll
    for (int m = 0; m < 2; ++m)
#pragma unroll
        for (int r = 0; r < 4; ++r) {
            const int rw = rg*32 + m*16 + lq*4 + r;
            const float rinv = 1.0f / (s_rs[0][rw] + s_rs[1][rw] + s_rs[2][rw] + s_rs[3][rw]);
            float* o = out + (size_t)(row0 + rw) * KCL + cg*64 + l15;
#pragma unroll
            for (int n = 0; n < 4; ++n)
                o[n * 16] = acc[m][n][r] * rinv;
        }
}

extern "C" void kernel_launch(void* const* d_in, const int* in_sizes, int n_in,
                              void* d_out, int out_size, void* d_ws, size_t ws_size,
                              hipStream_t stream) {
    const float* x  = (const float*)d_in[0];
    const float* cl = (const float*)d_in[1];
    float* out = (float*)d_out;
    short* wsB  = (short*)d_ws;
    float* wsC2 = (float*)((char*)d_ws + (size_t)NTILES * BTILE * sizeof(short)); // +256 KB

    prep<<<80, 256, 0, stream>>>(cl, wsB, wsC2);
    const int B = in_sizes[0] / DDIM;     // 65536
    dec_main<<<B / BM, NT, 0, stream>>>(x, wsB, wsC2, out);
}